// Round 21
// baseline (189.185 us; speedup 1.0000x reference)
//
#include <hip/hip_runtime.h>
#include <hip/hip_bf16.h>
#include <stdint.h>

typedef __attribute__((ext_vector_type(8))) short bf16x8;
typedef __attribute__((ext_vector_type(4))) float f32x4;
typedef __attribute__((ext_vector_type(16))) float f32x16;

#define N_IMG 32
#define CIN 128
#define COUT 256
#define HH 56
#define HW (HH*HH)            // 3136
#define HP 58
#define PXTOT (N_IMG*HW)      // 100352
#define NT 36                 // K tiles of 32 (9 offsets x 4 c-blocks)

// ws layout (bytes)
#define XP_BYTES    27557888u   // 32*58*58*128*2
#define WT_BYTES    589824u     // 36*256*32*2
#define INV_BYTES   12544u
#define STATS_BYTES 2048u
#define WS_MIN      (XP_BYTES + WT_BYTES + INV_BYTES + STATS_BYTES)
#define Y_BYTES     51380224u   // 256*100352*2

__device__ __forceinline__ unsigned short f2bf(float f) {
  unsigned int u = __builtin_bit_cast(unsigned int, f);
  unsigned int r = u + 0x7FFFu + ((u >> 16) & 1u);
  return (unsigned short)(r >> 16);
}
__device__ __forceinline__ float bf2f(unsigned short s) {
  return __builtin_bit_cast(float, (unsigned int)s << 16);
}
__device__ __forceinline__ void gload_lds16(const void* g, void* l) {
  __builtin_amdgcn_global_load_lds((const __attribute__((address_space(1))) void*)g,
                                   (__attribute__((address_space(3))) void*)l, 16, 0, 0);
}

#define BAR()    __builtin_amdgcn_s_barrier()
#define WAITV2() asm volatile("s_waitcnt vmcnt(2)" ::: "memory")
#define WAITV0() asm volatile("s_waitcnt vmcnt(0)" ::: "memory")
#define SCHEDB() __builtin_amdgcn_sched_barrier(0)

// weights relayout wt[kk][co][32] (kk = o*4+cb), + inverse perm, + stats zero
__global__ __launch_bounds__(256) void wcvt_kernel(const float* __restrict__ w,
                                                   unsigned short* __restrict__ wt,
                                                   const int* __restrict__ perm,
                                                   int* __restrict__ inv,
                                                   float* __restrict__ stats) {
  int i = blockIdx.x * 256 + threadIdx.x;     // 0..294911
  if (i < HW) inv[perm[i]] = i;
  if (i < 512) stats[i] = 0.f;
  if (i >= NT * COUT * 32) return;
  int kk = i >> 13;
  int r = i & 8191;
  int co = r >> 5, cl = r & 31;
  int o = kk >> 2, cb = kk & 3;
  int c = cb * 32 + cl;
  wt[i] = f2bf(w[(co * CIN + c) * 9 + o]);
}

// permute+pad+bf16 x -> xp NHWC [32][58][58][128]; also zeros the pad ring
__global__ __launch_bounds__(256) void pad_perm_kernel(const float* __restrict__ x,
                                                       const int* __restrict__ inv,
                                                       unsigned short* __restrict__ xp) {
  __shared__ unsigned short T[64 * 128];
  __shared__ int dest_off[64];
  int b = blockIdx.x;            // 0..1567
  int n = b / 49;
  int k = b % 49;
  int s0 = k * 64;
  int t = threadIdx.x;

  // zero pad ring: 228 pad-pixels/image, 5 per block, 32 threads (8B) each
  if (t < 160) {
    int pi = k * 5 + (t >> 5);
    if (pi < 228) {
      int h, w2;
      if (pi < 58)       { h = 0;            w2 = pi; }
      else if (pi < 116) { h = 57;           w2 = pi - 58; }
      else if (pi < 172) { h = pi - 116 + 1; w2 = 0; }
      else               { h = pi - 172 + 1; w2 = 57; }
      uint2 z = {0u, 0u};
      *(uint2*)(xp + (size_t)((n * HP + h) * HP + w2) * CIN + (t & 31) * 4) = z;
    }
  }

  if (t < 64) {
    int s = inv[s0 + t];
    int h = s / HH, w = s % HH;
    dest_off[t] = ((n * HP + h + 1) * HP + (w + 1)) * CIN;
  }
  const float* xplane = x + (size_t)n * CIN * HW;
  #pragma unroll
  for (int i = 0; i < 32; ++i) {
    int idx = i * 256 + t;
    int c = idx >> 6, j = idx & 63;
    float v = xplane[c * HW + s0 + j];
    int byte = j * 256 + ((2 * c) ^ ((j & 7) << 4));
    *(unsigned short*)((char*)T + byte) = f2bf(v);
  }
  __syncthreads();
  #pragma unroll
  for (int i = 0; i < 4; ++i) {
    int u = i * 256 + t;
    int j = u >> 4, chunk = u & 15;
    int byte = j * 256 + ((chunk * 16) ^ ((j & 7) << 4));
    bf16x8 v = *(const bf16x8*)((const char*)T + byte);
    *(bf16x8*)(xp + dest_off[j] + chunk * 8) = v;
  }
}

// ---- implicit-GEMM conv: 128co x 256px tile, BK=32, 512 thr (8 waves 2x4) --
// r16 banked schedule + 32x32x16 MFMA (r19 layout, silicon-verified) with the
// FIXED rotation swizzle: f(row) = ((row>>1) + (row>>4)) & 3 — breaks the
// row/row+16 aliasing that gave r19 its 7.3M bank conflicts. Staging inverse:
// lg = (p - f(r)) & 3 = ((t&3) - (t>>3) - (t>>6)) & 3 (A and B row bases are
// 0 mod 16/4 so one formula serves both). Reads add compile-time 2*mt / 2*nt
// from tile base>>4. 8 MFMA/phase (vs 16), same 8 ds_read_b128/phase.
template<int YMODE>
__global__ __launch_bounds__(512, 2) void conv_kernel(const unsigned short* __restrict__ xp,
                                                      const unsigned short* __restrict__ wt,
                                                      unsigned short* __restrict__ ybf,
                                                      float* __restrict__ yf32,
                                                      float* __restrict__ stats) {
  extern __shared__ unsigned short lds[];   // 32768 shorts: A[2][4096] | B[3][8192]
  int t = threadIdx.x;                      // 0..511
  int lane = t & 63, wid = t >> 6;          // 8 waves
  int wm = wid >> 2, wn = wid & 3;          // co half (64), px quadrant (64)
  int l31 = lane & 31, h5 = lane >> 5;
  int phys = blockIdx.x;
  int b = (phys & 7) * 98 + (phys >> 3);    // XCD swizzle (784 = 8*98, bijective)
  int pT = b >> 1;
  int coT = b & 1;
  int p0 = pT * 256;

  // ---- staging precomputes (fixed inverse swizzle) ----
  int lg = ((t & 3) - (t >> 3) - (t >> 6)) & 3;  // logical chunk at phys p=t&3
  int aoff = (t >> 2) * 32 + lg * 8;        // A src offset within a kk-slab
  int adst = t * 8;
  int bsrc[2], bdst[2];
  #pragma unroll
  for (int i = 0; i < 2; ++i) {
    int r = i * 128 + (t >> 2);             // B row = px-local 0..255
    int px = p0 + r;
    int n = px / HW, s = px % HW;
    int hi = s / HH, wi = s % HH;
    bsrc[i] = ((n * HP + hi) * HP + wi) * CIN + lg * 8;
    bdst[i] = i * 4096 + t * 8;
  }
  const unsigned short* wbase = wt + coT * 128 * 32;

  auto stageA = [&](int kt) {
    gload_lds16(wbase + kt * 8192 + aoff, lds + (kt & 1) * 4096 + adst);
  };
  auto stageB = [&](int kt, int buf) {
    int o = kt >> 2, cb = kt & 3;
    int koff = ((o / 3) * HP + (o % 3)) * CIN + cb * 32;
    unsigned short* d = lds + 8192 + buf * 8192;
    gload_lds16(xp + bsrc[0] + koff, d + bdst[0]);
    gload_lds16(xp + bsrc[1] + koff, d + bdst[1]);
  };

  // ---- ds_read precomputes (32x32x16 layout; fixed per-tile rotation) ----
  // logical k-chunk c = kh*2 + h5; phys = (c + f(row)) & 3 with
  // f(row) = (l31>>1) + (l31>>4) + 2*tile  (tile = mt for A, nt for B)
  int fr = (l31 >> 1) + (l31 >> 4);
  int pcsA[2][2], pcsB[2][2];               // [tile][kh]
  #pragma unroll
  for (int tl = 0; tl < 2; ++tl)
    #pragma unroll
    for (int kh = 0; kh < 2; ++kh) {
      int c = kh * 2 + h5;
      pcsA[tl][kh] = ((c + fr + 2 * tl) & 3) * 8;
      pcsB[tl][kh] = ((c + fr + 2 * tl) & 3) * 8;
    }
  int arow0 = (wm * 64 + l31) * 32;         // + mt*32*32
  int brow0 = (wn * 64 + l31) * 32;         // + nt*32*32

  bf16x8 afr[2][2], bfr[2][2];              // [mt|nt][kh]
  f32x16 acc[2][2];
  #pragma unroll
  for (int m = 0; m < 2; ++m)
    #pragma unroll
    for (int n = 0; n < 2; ++n) acc[m][n] = (f32x16)0.f;

#define LDA_ALL { _Pragma("unroll") for (int mt = 0; mt < 2; ++mt) { \
    afr[mt][0] = *(const bf16x8*)(curA + arow0 + mt * 1024 + pcsA[mt][0]); \
    afr[mt][1] = *(const bf16x8*)(curA + arow0 + mt * 1024 + pcsA[mt][1]); } }
#define LDB_ALL { _Pragma("unroll") for (int nt = 0; nt < 2; ++nt) { \
    bfr[nt][0] = *(const bf16x8*)(curB + brow0 + nt * 1024 + pcsB[nt][0]); \
    bfr[nt][1] = *(const bf16x8*)(curB + brow0 + nt * 1024 + pcsB[nt][1]); } }
#define MFMA_ALL { _Pragma("unroll") for (int kh = 0; kh < 2; ++kh) \
    _Pragma("unroll") for (int mt = 0; mt < 2; ++mt) \
    _Pragma("unroll") for (int nt = 0; nt < 2; ++nt) \
      acc[mt][nt] = __builtin_amdgcn_mfma_f32_32x32x16_bf16(afr[mt][kh], bfr[nt][kh], acc[mt][nt], 0, 0, 0); }

  // ---- prologue: A(0)->A0, B(0)->B0, B(1)->B1 (5 loads/thread) ----
  stageA(0);
  stageB(0, 0);
  stageB(1, 1);
  WAITV2();    // A(0),B(0) landed; B(1)'s 2 loads in flight
  BAR();

  int pb = 0;                                // kt % 3
  #pragma unroll 1
  for (int kt = 0; kt < NT; ++kt) {
    const unsigned short* curA = lds + (kt & 1) * 4096;
    const unsigned short* curB = lds + 8192 + pb * 8192;
    bool st1 = (kt + 1) < NT;
    bool st2 = (kt + 2) < NT;
    int pb2 = pb + 2; if (pb2 >= 3) pb2 -= 3; // (kt+2) % 3
    // single phase: 8 frag reads + both stages; MFMAs below with
    // compiler-managed counted lgkm (no full drain); one barrier.
    LDA_ALL; LDB_ALL;
    if (st1) stageA(kt + 1);
    if (st2) stageB(kt + 2, pb2);
    SCHEDB();                                // pin: loads issued above MFMAs
    MFMA_ALL;
    if (st2) { WAITV2(); } else if (st1) { WAITV0(); }
    BAR();
    pb = (pb + 1 == 3) ? 0 : pb + 1;
  }
#undef LDA_ALL
#undef LDB_ALL
#undef MFMA_ALL

  // ---- fused BN partial stats: reduce over the 32 cols (px) per half ----
  float ps1[2][16], ps2[2][16];
  #pragma unroll
  for (int mt = 0; mt < 2; ++mt)
    #pragma unroll
    for (int rg = 0; rg < 16; ++rg) {
      float a = 0.f, b2 = 0.f;
      #pragma unroll
      for (int nt = 0; nt < 2; ++nt) { float v = acc[mt][nt][rg]; a += v; b2 += v * v; }
      #pragma unroll
      for (int off = 1; off < 32; off <<= 1) {
        a  += __shfl_xor(a, off, 64);
        b2 += __shfl_xor(b2, off, 64);
      }
      ps1[mt][rg] = a; ps2[mt][rg] = b2;
    }

  // ---- y store: px = p0 + wn*64 + nt*32 + l31;
  //      co = coT*128 + wm*64 + mt*32 + (rg&3) + 8*(rg>>2) + 4*h5 ----
  #pragma unroll
  for (int nt = 0; nt < 2; ++nt) {
    int px = p0 + wn * 64 + nt * 32 + l31;
    if (YMODE == 1) {
      #pragma unroll
      for (int mt = 0; mt < 2; ++mt) {
        int cob = coT * 128 + wm * 64 + mt * 32 + 4 * h5;
        #pragma unroll
        for (int rg = 0; rg < 16; ++rg) {
          int co = cob + (rg & 3) + 8 * (rg >> 2);
          ybf[(size_t)co * PXTOT + px] = f2bf(acc[mt][nt][rg]);
        }
      }
    } else {
      int nimg = px / HW, s = px % HW;
      float* obase = yf32 + (size_t)nimg * COUT * HW + s;
      #pragma unroll
      for (int mt = 0; mt < 2; ++mt) {
        int cob = coT * 128 + wm * 64 + mt * 32 + 4 * h5;
        #pragma unroll
        for (int rg = 0; rg < 16; ++rg) {
          int co = cob + (rg & 3) + 8 * (rg >> 2);
          obase[(size_t)co * HW] = acc[mt][nt][rg];
        }
      }
    }
  }

  // ---- combine stats across 8 waves in LDS, one atomic pair per co ----
  float* sb = (float*)lds;   // s1[128][4], s2[128][4] = 4KB
  if (l31 == 0) {            // lanes 0 and 32 write (disjoint rows via h5)
    #pragma unroll
    for (int mt = 0; mt < 2; ++mt) {
      int clb = wm * 64 + mt * 32 + 4 * h5;
      #pragma unroll
      for (int rg = 0; rg < 16; ++rg) {
        int cl = clb + (rg & 3) + 8 * (rg >> 2);   // co-local 0..127
        sb[cl * 4 + wn] = ps1[mt][rg];
        sb[512 + cl * 4 + wn] = ps2[mt][rg];
      }
    }
  }
  BAR();
  if (t < 128) {
    int co = coT * 128 + t;
    float a  = sb[t * 4] + sb[t * 4 + 1] + sb[t * 4 + 2] + sb[t * 4 + 3];
    float b2 = sb[512 + t * 4] + sb[512 + t * 4 + 1] + sb[512 + t * 4 + 2] + sb[512 + t * 4 + 3];
    atomicAdd(&stats[co], a);
    atomicAdd(&stats[256 + co], b2);
  }
}

// y bf16 [co][px] -> out fp32 NCHW, BN(params folded)+ReLU
__global__ __launch_bounds__(256) void bnrelu1_kernel(const unsigned short* __restrict__ y,
                                                      const float* __restrict__ stats,
                                                      const float* __restrict__ gamma,
                                                      const float* __restrict__ beta,
                                                      float* __restrict__ out) {
  int idx = blockIdx.x * 256 + threadIdx.x;   // 8-px units
  const int UN = PXTOT / 8;                   // 12544
  int co = idx / UN;
  int rem = idx - co * UN;
  float cnt = (float)PXTOT;
  float mean = stats[co] / cnt;
  float var = stats[256 + co] / cnt - mean * mean;
  float sc = gamma[co] * rsqrtf(var + 1e-5f);
  float sh = beta[co] - mean * sc;
  bf16x8 v = *(const bf16x8*)(y + (size_t)co * PXTOT + rem * 8);
  int px0 = rem * 8;
  int n = px0 / HW, s = px0 - n * HW;
  float* o = out + ((size_t)n * COUT + co) * HW + s;
  float4 r0, r1;
  r0.x = fmaxf(bf2f((unsigned short)v[0]) * sc + sh, 0.f);
  r0.y = fmaxf(bf2f((unsigned short)v[1]) * sc + sh, 0.f);
  r0.z = fmaxf(bf2f((unsigned short)v[2]) * sc + sh, 0.f);
  r0.w = fmaxf(bf2f((unsigned short)v[3]) * sc + sh, 0.f);
  r1.x = fmaxf(bf2f((unsigned short)v[4]) * sc + sh, 0.f);
  r1.y = fmaxf(bf2f((unsigned short)v[5]) * sc + sh, 0.f);
  r1.z = fmaxf(bf2f((unsigned short)v[6]) * sc + sh, 0.f);
  r1.w = fmaxf(bf2f((unsigned short)v[7]) * sc + sh, 0.f);
  ((float4*)o)[0] = r0;
  ((float4*)o)[1] = r1;
}

// fallback: in-place BN(folded)+ReLU on fp32 NCHW in d_out
__global__ __launch_bounds__(256) void bnrelu0_kernel(float* __restrict__ y,
                                                      const float* __restrict__ stats,
                                                      const float* __restrict__ gamma,
                                                      const float* __restrict__ beta) {
  int idx = blockIdx.x * 256 + threadIdx.x;   // float4 units, grid exact
  int plane = idx / (HW / 4);
  int co = plane & 255;
  float cnt = (float)PXTOT;
  float mean = stats[co] / cnt;
  float var = stats[256 + co] / cnt - mean * mean;
  float sc = gamma[co] * rsqrtf(var + 1e-5f);
  float sh = beta[co] - mean * sc;
  float4 v = ((float4*)y)[idx];
  v.x = fmaxf(v.x * sc + sh, 0.f);
  v.y = fmaxf(v.y * sc + sh, 0.f);
  v.z = fmaxf(v.z * sc + sh, 0.f);
  v.w = fmaxf(v.w * sc + sh, 0.f);
  ((float4*)y)[idx] = v;
}

extern "C" void kernel_launch(void* const* d_in, const int* in_sizes, int n_in,
                              void* d_out, int out_size, void* d_ws, size_t ws_size,
                              hipStream_t stream) {
  const float* x     = (const float*)d_in[0];
  const float* w     = (const float*)d_in[1];
  const float* gamma = (const float*)d_in[2];
  const float* beta  = (const float*)d_in[3];
  const int*   perm  = (const int*)d_in[4];
  float* out = (float*)d_out;
  char* ws = (char*)d_ws;

  unsigned short* xp = (unsigned short*)ws;
  unsigned short* wt = (unsigned short*)(ws + XP_BYTES);
  int* inv           = (int*)(ws + XP_BYTES + WT_BYTES);
  float* stats       = (float*)(ws + XP_BYTES + WT_BYTES + INV_BYTES);
  unsigned short* y  = (unsigned short*)(ws + WS_MIN);
  bool ymode = ws_size >= (size_t)WS_MIN + Y_BYTES;

  hipFuncSetAttribute(reinterpret_cast<const void*>(conv_kernel<1>),
                      hipFuncAttributeMaxDynamicSharedMemorySize, 65536);
  hipFuncSetAttribute(reinterpret_cast<const void*>(conv_kernel<0>),
                      hipFuncAttributeMaxDynamicSharedMemorySize, 65536);

  wcvt_kernel<<<1152, 256, 0, stream>>>(w, wt, perm, inv, stats);
  pad_perm_kernel<<<N_IMG * 49, 256, 0, stream>>>(x, inv, xp);
  if (ymode) {
    conv_kernel<1><<<784, 512, 65536, stream>>>(xp, wt, y, out, stats);
    bnrelu1_kernel<<<COUT * (PXTOT / 8) / 256, 256, 0, stream>>>(y, stats, gamma, beta, out);
  } else {
    conv_kernel<0><<<784, 512, 65536, stream>>>(xp, wt, (unsigned short*)out, out, stats);
    bnrelu0_kernel<<<N_IMG * COUT * HW / 4 / 256, 256, 0, stream>>>(out, stats, gamma, beta);
  }
}

// Round 22
// 119.493 us; speedup vs baseline: 1.5832x; 1.5832x over previous
//
#include <hip/hip_runtime.h>
#include <hip/hip_bf16.h>
#include <stdint.h>

typedef __attribute__((ext_vector_type(8))) short bf16x8;
typedef __attribute__((ext_vector_type(4))) float f32x4;

#define N_IMG 32
#define CIN 128
#define COUT 256
#define HH 56
#define HW (HH*HH)            // 3136
#define HP 58
#define PXTOT (N_IMG*HW)      // 100352
#define NT 36                 // K tiles of 32 (9 offsets x 4 c-blocks)

// ws layout (bytes)
#define XP_BYTES    27557888u   // 32*58*58*128*2
#define WT_BYTES    589824u     // 36*256*32*2
#define INV_BYTES   12544u
#define STATS_BYTES 2048u
#define WS_MIN      (XP_BYTES + WT_BYTES + INV_BYTES + STATS_BYTES)
#define Y_BYTES     51380224u   // 256*100352*2

__device__ __forceinline__ unsigned short f2bf(float f) {
  unsigned int u = __builtin_bit_cast(unsigned int, f);
  unsigned int r = u + 0x7FFFu + ((u >> 16) & 1u);
  return (unsigned short)(r >> 16);
}
__device__ __forceinline__ float bf2f(unsigned short s) {
  return __builtin_bit_cast(float, (unsigned int)s << 16);
}
__device__ __forceinline__ void gload_lds16(const void* g, void* l) {
  __builtin_amdgcn_global_load_lds((const __attribute__((address_space(1))) void*)g,
                                   (__attribute__((address_space(3))) void*)l, 16, 0, 0);
}

#define BAR()    __builtin_amdgcn_s_barrier()
#define WAITV2() asm volatile("s_waitcnt vmcnt(2)" ::: "memory")
#define WAITV0() asm volatile("s_waitcnt vmcnt(0)" ::: "memory")
#define SCHEDB() __builtin_amdgcn_sched_barrier(0)

// weights relayout wt[kk][co][32] (kk = o*4+cb), + inverse perm, + stats zero
__global__ __launch_bounds__(256) void wcvt_kernel(const float* __restrict__ w,
                                                   unsigned short* __restrict__ wt,
                                                   const int* __restrict__ perm,
                                                   int* __restrict__ inv,
                                                   float* __restrict__ stats) {
  int i = blockIdx.x * 256 + threadIdx.x;     // 0..294911
  if (i < HW) inv[perm[i]] = i;
  if (i < 512) stats[i] = 0.f;
  if (i >= NT * COUT * 32) return;
  int kk = i >> 13;
  int r = i & 8191;
  int co = r >> 5, cl = r & 31;
  int o = kk >> 2, cb = kk & 3;
  int c = cb * 32 + cl;
  wt[i] = f2bf(w[(co * CIN + c) * 9 + o]);
}

// permute+pad+bf16 x -> xp NHWC [32][58][58][128]; also zeros the pad ring
__global__ __launch_bounds__(256) void pad_perm_kernel(const float* __restrict__ x,
                                                       const int* __restrict__ inv,
                                                       unsigned short* __restrict__ xp) {
  __shared__ unsigned short T[64 * 128];
  __shared__ int dest_off[64];
  int b = blockIdx.x;            // 0..1567
  int n = b / 49;
  int k = b % 49;
  int s0 = k * 64;
  int t = threadIdx.x;

  // zero pad ring: 228 pad-pixels/image, 5 per block, 32 threads (8B) each
  if (t < 160) {
    int pi = k * 5 + (t >> 5);
    if (pi < 228) {
      int h, w2;
      if (pi < 58)       { h = 0;            w2 = pi; }
      else if (pi < 116) { h = 57;           w2 = pi - 58; }
      else if (pi < 172) { h = pi - 116 + 1; w2 = 0; }
      else               { h = pi - 172 + 1; w2 = 57; }
      uint2 z = {0u, 0u};
      *(uint2*)(xp + (size_t)((n * HP + h) * HP + w2) * CIN + (t & 31) * 4) = z;
    }
  }

  if (t < 64) {
    int s = inv[s0 + t];
    int h = s / HH, w = s % HH;
    dest_off[t] = ((n * HP + h + 1) * HP + (w + 1)) * CIN;
  }
  const float* xplane = x + (size_t)n * CIN * HW;
  #pragma unroll
  for (int i = 0; i < 32; ++i) {
    int idx = i * 256 + t;
    int c = idx >> 6, j = idx & 63;
    float v = xplane[c * HW + s0 + j];
    int byte = j * 256 + ((2 * c) ^ ((j & 7) << 4));
    *(unsigned short*)((char*)T + byte) = f2bf(v);
  }
  __syncthreads();
  #pragma unroll
  for (int i = 0; i < 4; ++i) {
    int u = i * 256 + t;
    int j = u >> 4, chunk = u & 15;
    int byte = j * 256 + ((chunk * 16) ^ ((j & 7) << 4));
    bf16x8 v = *(const bf16x8*)((const char*)T + byte);
    *(bf16x8*)(xp + dest_off[j] + chunk * 8) = v;
  }
}

// ---- implicit-GEMM conv: 128co x 256px tile, BK=32, 512 thr (8 waves 2x4) --
// Banked best (r16): single phase per K-tile {8 ds_reads, stages,
// sched_barrier (loads pinned above), MFMA cluster with COMPILER-counted
// lgkm interleave, counted vmcnt(2), ONE barrier}. A dbuf / B triple-buf ->
// no same-phase buffer conflicts; prior-phase ds_reads drained by their
// consuming MFMAs' compiler waits before end-BAR. 3 loads/phase; steady
// WAITV2, tail WAITV0. Rotation swizzle on 16B chunks (silicon-verified).
// 16x16x32 MFMA kept deliberately: 16 independent accumulators/phase beat
// 32x32's 4 chained ones in this latency-bound regime (r19/r21 falsified).
template<int YMODE>
__global__ __launch_bounds__(512, 2) void conv_kernel(const unsigned short* __restrict__ xp,
                                                      const unsigned short* __restrict__ wt,
                                                      unsigned short* __restrict__ ybf,
                                                      float* __restrict__ yf32,
                                                      float* __restrict__ stats) {
  extern __shared__ unsigned short lds[];   // 32768 shorts: A[2][4096] | B[3][8192]
  int t = threadIdx.x;                      // 0..511
  int lane = t & 63, wid = t >> 6;          // 8 waves
  int wm = wid >> 2, wn = wid & 3;          // co half (64), px quadrant (64)
  int l = lane & 15, g = lane >> 4;
  int phys = blockIdx.x;
  int b = (phys & 7) * 98 + (phys >> 3);    // XCD swizzle (784 = 8*98, bijective)
  int pT = b >> 1;
  int coT = b & 1;
  int p0 = pT * 256;

  // ---- staging precomputes ----
  int lg = ((t & 3) - (lane >> 3)) & 3;     // inverse swizzle chunk
  int aoff = (t >> 2) * 32 + lg * 8;        // A src offset within a kk-slab
  int adst = t * 8;
  int bsrc[2], bdst[2];
  #pragma unroll
  for (int i = 0; i < 2; ++i) {
    int r = i * 128 + (t >> 2);             // B row = px-local 0..255
    int px = p0 + r;
    int n = px / HW, s = px % HW;
    int hi = s / HH, wi = s % HH;
    bsrc[i] = ((n * HP + hi) * HP + wi) * CIN + lg * 8;
    bdst[i] = i * 4096 + t * 8;
  }
  const unsigned short* wbase = wt + coT * 128 * 32;

  auto stageA = [&](int kt) {
    gload_lds16(wbase + kt * 8192 + aoff, lds + (kt & 1) * 4096 + adst);
  };
  auto stageB = [&](int kt, int buf) {
    int o = kt >> 2, cb = kt & 3;
    int koff = ((o / 3) * HP + (o % 3)) * CIN + cb * 32;
    unsigned short* d = lds + 8192 + buf * 8192;
    gload_lds16(xp + bsrc[0] + koff, d + bdst[0]);
    gload_lds16(xp + bsrc[1] + koff, d + bdst[1]);
  };

  // ---- ds_read precomputes ----
  int pcs = ((g + (l >> 1)) & 3) * 8;       // swizzled k-chunk for logical g
  int arow = (wm * 64 + l) * 32 + pcs;      // + mm*16*32 (A buf: 128 rows)
  int brow = (wn * 64 + l) * 32 + pcs;      // + nn*16*32 (B buf: 256 rows)

  bf16x8 afr[4], bfr[4];
  f32x4 acc[4][4];
  #pragma unroll
  for (int m = 0; m < 4; ++m)
    #pragma unroll
    for (int n = 0; n < 4; ++n) acc[m][n] = (f32x4)0.f;

#define LDA_ALL { _Pragma("unroll") for (int mm = 0; mm < 4; ++mm) \
    afr[mm] = *(const bf16x8*)(curA + arow + mm * 16 * 32); }
#define LDB_ALL { _Pragma("unroll") for (int nn = 0; nn < 4; ++nn) \
    bfr[nn] = *(const bf16x8*)(curB + brow + nn * 16 * 32); }
#define MFMA_ALL { _Pragma("unroll") for (int mm = 0; mm < 4; ++mm) \
    _Pragma("unroll") for (int nn = 0; nn < 4; ++nn) \
      acc[mm][nn] = __builtin_amdgcn_mfma_f32_16x16x32_bf16(afr[mm], bfr[nn], acc[mm][nn], 0, 0, 0); }

  // ---- prologue: A(0)->A0, B(0)->B0, B(1)->B1 (5 loads/thread) ----
  stageA(0);
  stageB(0, 0);
  stageB(1, 1);
  WAITV2();    // A(0),B(0) landed; B(1)'s 2 loads in flight
  BAR();

  int pb = 0;                                // kt % 3
  #pragma unroll 1
  for (int kt = 0; kt < NT; ++kt) {
    const unsigned short* curA = lds + (kt & 1) * 4096;
    const unsigned short* curB = lds + 8192 + pb * 8192;
    bool st1 = (kt + 1) < NT;
    bool st2 = (kt + 2) < NT;
    int pb2 = pb + 2; if (pb2 >= 3) pb2 -= 3; // (kt+2) % 3
    // single phase: 8 frag reads + both stages; MFMAs below with
    // compiler-managed counted lgkm (no full drain); one barrier.
    LDA_ALL; LDB_ALL;
    if (st1) stageA(kt + 1);
    if (st2) stageB(kt + 2, pb2);
    SCHEDB();                                // pin: loads issued above MFMAs
    MFMA_ALL;
    if (st2) { WAITV2(); } else if (st1) { WAITV0(); }
    BAR();
    pb = (pb + 1 == 3) ? 0 : pb + 1;
  }
#undef LDA_ALL
#undef LDB_ALL
#undef MFMA_ALL

  // ---- fused BN partial stats (reduce over 16 px lanes l) ----
  float ps1[4][4], ps2[4][4];
  #pragma unroll
  for (int m = 0; m < 4; ++m)
    #pragma unroll
    for (int j = 0; j < 4; ++j) {
      float a = 0.f, b2 = 0.f;
      #pragma unroll
      for (int n = 0; n < 4; ++n) { float v = acc[m][n][j]; a += v; b2 += v * v; }
      #pragma unroll
      for (int off = 1; off < 16; off <<= 1) {
        a  += __shfl_xor(a, off, 64);
        b2 += __shfl_xor(b2, off, 64);
      }
      ps1[m][j] = a; ps2[m][j] = b2;
    }

  // ---- y store: px = p0 + wn*64 + n*16 + l; co = coT*128 + wm*64 + m*16 + g*4 + j
  #pragma unroll
  for (int n = 0; n < 4; ++n) {
    int px = p0 + wn * 64 + n * 16 + l;
    if (YMODE == 1) {
      #pragma unroll
      for (int m = 0; m < 4; ++m) {
        int co = coT * 128 + wm * 64 + m * 16 + g * 4;
        #pragma unroll
        for (int j = 0; j < 4; ++j)
          ybf[(size_t)(co + j) * PXTOT + px] = f2bf(acc[m][n][j]);
      }
    } else {
      int nimg = px / HW, s = px % HW;
      float* obase = yf32 + (size_t)nimg * COUT * HW + s;
      #pragma unroll
      for (int m = 0; m < 4; ++m) {
        int co = coT * 128 + wm * 64 + m * 16 + g * 4;
        #pragma unroll
        for (int j = 0; j < 4; ++j)
          obase[(size_t)(co + j) * HW] = acc[m][n][j];
      }
    }
  }

  // ---- combine stats across 8 waves in LDS, one atomic pair per co ----
  float* sb = (float*)lds;   // s1[128][4], s2[128][4] = 4KB
  if (l == 0) {
    #pragma unroll
    for (int m = 0; m < 4; ++m)
      #pragma unroll
      for (int j = 0; j < 4; ++j) {
        int cl = wm * 64 + m * 16 + g * 4 + j;   // co-local 0..127
        sb[cl * 4 + wn] = ps1[m][j];
        sb[512 + cl * 4 + wn] = ps2[m][j];
      }
  }
  BAR();
  if (t < 128) {
    int co = coT * 128 + t;
    float a  = sb[t * 4] + sb[t * 4 + 1] + sb[t * 4 + 2] + sb[t * 4 + 3];
    float b2 = sb[512 + t * 4] + sb[512 + t * 4 + 1] + sb[512 + t * 4 + 2] + sb[512 + t * 4 + 3];
    atomicAdd(&stats[co], a);
    atomicAdd(&stats[256 + co], b2);
  }
}

// y bf16 [co][px] -> out fp32 NCHW, BN(params folded)+ReLU
__global__ __launch_bounds__(256) void bnrelu1_kernel(const unsigned short* __restrict__ y,
                                                      const float* __restrict__ stats,
                                                      const float* __restrict__ gamma,
                                                      const float* __restrict__ beta,
                                                      float* __restrict__ out) {
  int idx = blockIdx.x * 256 + threadIdx.x;   // 8-px units
  const int UN = PXTOT / 8;                   // 12544
  int co = idx / UN;
  int rem = idx - co * UN;
  float cnt = (float)PXTOT;
  float mean = stats[co] / cnt;
  float var = stats[256 + co] / cnt - mean * mean;
  float sc = gamma[co] * rsqrtf(var + 1e-5f);
  float sh = beta[co] - mean * sc;
  bf16x8 v = *(const bf16x8*)(y + (size_t)co * PXTOT + rem * 8);
  int px0 = rem * 8;
  int n = px0 / HW, s = px0 - n * HW;
  float* o = out + ((size_t)n * COUT + co) * HW + s;
  float4 r0, r1;
  r0.x = fmaxf(bf2f((unsigned short)v[0]) * sc + sh, 0.f);
  r0.y = fmaxf(bf2f((unsigned short)v[1]) * sc + sh, 0.f);
  r0.z = fmaxf(bf2f((unsigned short)v[2]) * sc + sh, 0.f);
  r0.w = fmaxf(bf2f((unsigned short)v[3]) * sc + sh, 0.f);
  r1.x = fmaxf(bf2f((unsigned short)v[4]) * sc + sh, 0.f);
  r1.y = fmaxf(bf2f((unsigned short)v[5]) * sc + sh, 0.f);
  r1.z = fmaxf(bf2f((unsigned short)v[6]) * sc + sh, 0.f);
  r1.w = fmaxf(bf2f((unsigned short)v[7]) * sc + sh, 0.f);
  ((float4*)o)[0] = r0;
  ((float4*)o)[1] = r1;
}

// fallback: in-place BN(folded)+ReLU on fp32 NCHW in d_out
__global__ __launch_bounds__(256) void bnrelu0_kernel(float* __restrict__ y,
                                                      const float* __restrict__ stats,
                                                      const float* __restrict__ gamma,
                                                      const float* __restrict__ beta) {
  int idx = blockIdx.x * 256 + threadIdx.x;   // float4 units, grid exact
  int plane = idx / (HW / 4);
  int co = plane & 255;
  float cnt = (float)PXTOT;
  float mean = stats[co] / cnt;
  float var = stats[256 + co] / cnt - mean * mean;
  float sc = gamma[co] * rsqrtf(var + 1e-5f);
  float sh = beta[co] - mean * sc;
  float4 v = ((float4*)y)[idx];
  v.x = fmaxf(v.x * sc + sh, 0.f);
  v.y = fmaxf(v.y * sc + sh, 0.f);
  v.z = fmaxf(v.z * sc + sh, 0.f);
  v.w = fmaxf(v.w * sc + sh, 0.f);
  ((float4*)y)[idx] = v;
}

extern "C" void kernel_launch(void* const* d_in, const int* in_sizes, int n_in,
                              void* d_out, int out_size, void* d_ws, size_t ws_size,
                              hipStream_t stream) {
  const float* x     = (const float*)d_in[0];
  const float* w     = (const float*)d_in[1];
  const float* gamma = (const float*)d_in[2];
  const float* beta  = (const float*)d_in[3];
  const int*   perm  = (const int*)d_in[4];
  float* out = (float*)d_out;
  char* ws = (char*)d_ws;

  unsigned short* xp = (unsigned short*)ws;
  unsigned short* wt = (unsigned short*)(ws + XP_BYTES);
  int* inv           = (int*)(ws + XP_BYTES + WT_BYTES);
  float* stats       = (float*)(ws + XP_BYTES + WT_BYTES + INV_BYTES);
  unsigned short* y  = (unsigned short*)(ws + WS_MIN);
  bool ymode = ws_size >= (size_t)WS_MIN + Y_BYTES;

  hipFuncSetAttribute(reinterpret_cast<const void*>(conv_kernel<1>),
                      hipFuncAttributeMaxDynamicSharedMemorySize, 65536);
  hipFuncSetAttribute(reinterpret_cast<const void*>(conv_kernel<0>),
                      hipFuncAttributeMaxDynamicSharedMemorySize, 65536);

  wcvt_kernel<<<1152, 256, 0, stream>>>(w, wt, perm, inv, stats);
  pad_perm_kernel<<<N_IMG * 49, 256, 0, stream>>>(x, inv, xp);
  if (ymode) {
    conv_kernel<1><<<784, 512, 65536, stream>>>(xp, wt, y, out, stats);
    bnrelu1_kernel<<<COUT * (PXTOT / 8) / 256, 256, 0, stream>>>(y, stats, gamma, beta, out);
  } else {
    conv_kernel<0><<<784, 512, 65536, stream>>>(xp, wt, (unsigned short*)out, out, stats);
    bnrelu0_kernel<<<N_IMG * COUT * HW / 4 / 256, 256, 0, stream>>>(out, stats, gamma, beta);
  }
}